// Round 5
// baseline (725.510 us; speedup 1.0000x reference)
//
#include <hip/hip_runtime.h>
#include <hip/hip_bf16.h>

typedef __bf16 bf16;
typedef __bf16 bf16x4 __attribute__((ext_vector_type(4)));
typedef __bf16 bf16x8 __attribute__((ext_vector_type(8)));
typedef float f32x4 __attribute__((ext_vector_type(4)));

#define FENCE() asm volatile("" ::: "memory")
#define BARRIER() do { FENCE(); __builtin_amdgcn_s_barrier(); FENCE(); } while (0)

constexpr int UNITS = 8;
constexpr int BATCH = 65536;
constexpr int DIM   = 256;          // I == H == 256
constexpr int BM    = 256;          // rows per block (1 block/CU, 8 waves)
constexpr int BN    = 16;           // j-tile columns
constexpr int JT    = DIM / BN;     // 16 j-tiles
constexpr int KC    = 8;            // 8 k-chunks of 32
constexpr int TOTSS = UNITS * JT * KC;   // 1024 weight k-steps
constexpr int CHUNK = 6 * 64 * 8;   // 3072 bf16 per k-step (6 frags x 64 lanes x 8)
constexpr size_t WN = (size_t)UNITS * 3 * DIM * DIM;  // per weight tensor

__device__ __forceinline__ float sigmoidf_fast(float x) {
    return 1.0f / (1.0f + __expf(-x));
}
__device__ __forceinline__ float tanhf_fast(float x) {
    float y = fminf(fmaxf(x, -15.0f), 15.0f);
    float e = __expf(-2.0f * y);
    return (1.0f - e) / (1.0f + e);
}
// swizzled h tile (512B rows): XOR row bits into the 16B-slot bits
__device__ __forceinline__ unsigned hsoff(int row, int col) {
    return (unsigned)((row * DIM + col) * 2) ^ (unsigned)((row & 7) << 4);
}
__device__ __forceinline__ float bfbits2f(unsigned b) {
    return __builtin_bit_cast(float, b << 16);
}
__device__ __forceinline__ unsigned f2bfbits(float f) {
    return (unsigned)__builtin_bit_cast(unsigned short, (bf16)f);
}

// ---------------------------------------------------------------------------
// Pack weights into MFMA B-fragment stream order:
//   Wpk[ss][gi][lane][0..8) , ss = ((u*16+jt)*8+kc), gi: 0..2 = Wih gates,
//   3..5 = Whh gates.  Fragment content for lane (quad,l15):
//   W[g*256 + jt*16 + l15][kc*32 + quad*8 .. +8]  (same register contents the
//   R4 swizzled-LDS path delivered -> MFMA semantics unchanged).
// Plus combined biases bcomb[u][0..256)=r, [256..512)=z, [512..768)=n_i,
// [768..1024)=n_h.
__global__ void convert_kernel(const float* __restrict__ Wih,
                               const float* __restrict__ Whh,
                               const float* __restrict__ bih,
                               const float* __restrict__ bhh,
                               bf16* __restrict__ Wpk,
                               float* __restrict__ bcomb)
{
    const size_t W8 = 2 * WN / 8;   // 393216 fragment-threads
    size_t i = (size_t)blockIdx.x * blockDim.x + threadIdx.x;
    if (i < W8) {
        const int ss   = (int)(i / 384);
        const int r    = (int)(i % 384);
        const int gi   = r >> 6;
        const int lane = r & 63;
        const int kc = ss & 7, jt = (ss >> 3) & 15, u = ss >> 7;
        const int g  = (gi < 3) ? gi : gi - 3;
        const float* W = ((gi < 3) ? Wih : Whh) + (size_t)u * 3 * DIM * DIM;
        const int row = g * DIM + jt * BN + (lane & 15);
        const int col = kc * 32 + (lane >> 4) * 8;
        const float* s = W + (size_t)row * DIM + col;
        const float4 a = *(const float4*)(s);
        const float4 b = *(const float4*)(s + 4);
        bf16x8 v;
        v[0]=(bf16)a.x; v[1]=(bf16)a.y; v[2]=(bf16)a.z; v[3]=(bf16)a.w;
        v[4]=(bf16)b.x; v[5]=(bf16)b.y; v[6]=(bf16)b.z; v[7]=(bf16)b.w;
        *(bf16x8*)(Wpk + i * 8) = v;
    } else {
        size_t j = i - W8;
        if (j < (size_t)UNITS * 1024) {
            int u = (int)(j >> 10), t = (int)(j & 1023);
            const float* bi = bih + u * 768;
            const float* bh = bhh + u * 768;
            float v;
            if (t < 512)      v = bi[t] + bh[t];
            else if (t < 768) v = bi[t];
            else              v = bh[t - 256];
            bcomb[u * 1024 + t] = v;
        }
    }
}

// load the 6 B-fragments of k-step SS into a bf16x8[6] register group
#define LOADW(B6, SS) do {                                                   \
    const bf16* p_ = wl + (size_t)(SS) * CHUNK;                              \
    _Pragma("unroll")                                                        \
    for (int gi_ = 0; gi_ < 6; ++gi_)                                        \
        B6[gi_] = *(const bf16x8*)(p_ + gi_ * 512);                          \
} while (0)

// 12 MFMAs of one k-chunk (KCG compile-time); B6[0..2]=Wih, B6[3..5]=Whh
#define MFMA12(B6, KCG) do {                                                 \
    __builtin_amdgcn_s_setprio(1);                                           \
    _Pragma("unroll")                                                        \
    for (int mt_ = 0; mt_ < 2; ++mt_) {                                      \
        acc[0][mt_] = __builtin_amdgcn_mfma_f32_16x16x32_bf16(xf[mt_][KCG], B6[0], acc[0][mt_], 0, 0, 0); \
        acc[0][mt_] = __builtin_amdgcn_mfma_f32_16x16x32_bf16(hf[mt_][KCG], B6[3], acc[0][mt_], 0, 0, 0); \
        acc[1][mt_] = __builtin_amdgcn_mfma_f32_16x16x32_bf16(xf[mt_][KCG], B6[1], acc[1][mt_], 0, 0, 0); \
        acc[1][mt_] = __builtin_amdgcn_mfma_f32_16x16x32_bf16(hf[mt_][KCG], B6[4], acc[1][mt_], 0, 0, 0); \
        acc[2][mt_] = __builtin_amdgcn_mfma_f32_16x16x32_bf16(xf[mt_][KCG], B6[2], acc[2][mt_], 0, 0, 0); \
        acc[3][mt_] = __builtin_amdgcn_mfma_f32_16x16x32_bf16(hf[mt_][KCG], B6[5], acc[3][mt_], 0, 0, 0); \
    }                                                                        \
    __builtin_amdgcn_s_setprio(0);                                           \
} while (0)

// ---------------------------------------------------------------------------
// Fused 8-unit GRU chain, 1 block/CU, 8 waves, ZERO cooperative staging.
// Weights stream straight from global (pre-packed fragment order) into VGPRs
// with a depth-2 register double-buffer; all 8 waves read the same 6KB/step
// -> L1-served. No cross-wave data dependency exists, so the main loop has
// no vmcnt drains and no memory barriers; one raw s_barrier per jt only
// bounds wave drift (in-flight loads cross it freely).
__global__ __launch_bounds__(512, 2)
void gru_fused_kernel(const float* __restrict__ xg,     // [B,256] f32
                      const float* __restrict__ h0g,    // [256] f32
                      const bf16* __restrict__ Wpk,     // packed B-frag stream
                      const float* __restrict__ bcomb,  // [8,1024] f32
                      float* __restrict__ out)          // [B,256] f32
{
    __shared__ __align__(16) bf16 hs[BM * DIM];       // 128 KB (only LDS)

    const int tid  = threadIdx.x;
    const int wave = tid >> 6;      // 0..7
    const int lane = tid & 63;
    const int quad = lane >> 4;
    const int l15  = lane & 15;
    const int odd  = l15 & 1;
    const int m0   = blockIdx.x * BM;

    // ---- x m-tile -> persistent A-fragments (f32 load, bf16 convert) ----
    bf16x8 xf[2][8];
#pragma unroll
    for (int mt = 0; mt < 2; ++mt) {
        const int row = m0 + wave * 32 + mt * 16 + l15;
        const float* xr = xg + (size_t)row * DIM + quad * 8;
#pragma unroll
        for (int kc = 0; kc < 8; ++kc) {
            const float4 a = *(const float4*)(xr + kc * 32);
            const float4 b = *(const float4*)(xr + kc * 32 + 4);
            bf16x8 v;
            v[0]=(bf16)a.x; v[1]=(bf16)a.y; v[2]=(bf16)a.z; v[3]=(bf16)a.w;
            v[4]=(bf16)b.x; v[5]=(bf16)b.y; v[6]=(bf16)b.z; v[7]=(bf16)b.w;
            xf[mt][kc] = v;
        }
    }

    // ---- h0 -> hf A-fragments (broadcast) + hs init (own rows) ----
    bf16x8 hf[2][8];
#pragma unroll
    for (int kc = 0; kc < 8; ++kc) {
        const float4 a = *(const float4*)(h0g + kc * 32 + quad * 8);
        const float4 b = *(const float4*)(h0g + kc * 32 + quad * 8 + 4);
        bf16x8 v;
        v[0]=(bf16)a.x; v[1]=(bf16)a.y; v[2]=(bf16)a.z; v[3]=(bf16)a.w;
        v[4]=(bf16)b.x; v[5]=(bf16)b.y; v[6]=(bf16)b.z; v[7]=(bf16)b.w;
        hf[0][kc] = v;
        hf[1][kc] = v;
    }
#pragma unroll
    for (int mt = 0; mt < 2; ++mt)
#pragma unroll
        for (int kc = 0; kc < 8; ++kc)
            *(bf16x8*)((char*)hs + hsoff(wave * 32 + mt * 16 + l15,
                                         kc * 32 + quad * 8)) = hf[mt][kc];

    // ---- bias regs for (u=0, jt=0) ----
    float bc0, bc1, bc2, bc3;
    float bn0 = 0.f, bn1 = 0.f, bn2 = 0.f, bn3 = 0.f;
    {
        const float* bp = bcomb + l15;
        bc0 = bp[0]; bc1 = bp[256]; bc2 = bp[512]; bc3 = bp[768];
    }

    // ---- weight-stream prologue: prefetch k-steps 0 and 1 ----
    const bf16* wl = Wpk + (size_t)lane * 8;
    bf16x8 bw[2][6];
    LOADW(bw[0], 0);
    LOADW(bw[1], 1);

    for (int u = 0; u < UNITS; ++u) {
        for (int jt = 0; jt < JT; ++jt) {
            BARRIER();   // drift bound only: no vmcnt drain, loads stay in flight

            // biases folded into accumulator init
            f32x4 acc[4][2];
#pragma unroll
            for (int mt = 0; mt < 2; ++mt) {
                acc[0][mt] = (f32x4){bc0, bc0, bc0, bc0};
                acc[1][mt] = (f32x4){bc1, bc1, bc1, bc1};
                acc[2][mt] = (f32x4){bc2, bc2, bc2, bc2};
                acc[3][mt] = (f32x4){bc3, bc3, bc3, bc3};
            }
            const int sgb = (u * JT + jt) * KC;

#pragma unroll
            for (int kc = 0; kc < KC; ++kc) {
                // consume bw[kc&1] (k-step sgb+kc), then refill it with
                // k-step sgb+kc+2: depth-2 per-wave pipeline, compiler
                // inserts counted vmcnt waits.
                MFMA12(bw[kc & 1], kc);
                if (sgb + kc + 2 < TOTSS)
                    LOADW(bw[kc & 1], sgb + kc + 2);
                if (kc == 1) {   // prefetch next jt's biases
                    const int njt = (jt + 1) & 15;
                    const int nu  = (jt == JT - 1) ? u + 1 : u;
                    if (nu < UNITS) {
                        const float* bp = bcomb + nu * 1024 + njt * BN + l15;
                        bn0 = bp[0]; bn1 = bp[256]; bn2 = bp[512]; bn3 = bp[768];
                    }
                }
            }

            // ---- epilogue: activations, write h_new through to hs ----
            // hf regs still hold full h_prev, so writing hs per-jt is safe.
            // C/D layout: col = l15, row = quad*4 + i. Even/odd lane pairs
            // exchange halves so hs reads/writes are full-dword ops.
#pragma unroll
            for (int mt = 0; mt < 2; ++mt) {
                const int rbase = wave * 32 + mt * 16 + quad * 4;
                const int rowA  = rbase + 2 * odd;
                const int colb  = jt * BN + (l15 & ~1);
                const unsigned d0 = *(const unsigned*)((const char*)hs + hsoff(rowA,     colb));
                const unsigned d1 = *(const unsigned*)((const char*)hs + hsoff(rowA + 1, colb));
                const unsigned o0 = (unsigned)__shfl_xor((int)d0, 1);
                const unsigned o1 = (unsigned)__shfl_xor((int)d1, 1);
                const unsigned p0 = odd ? o0 : d0;
                const unsigned p1 = odd ? o1 : d1;
                const unsigned p2 = odd ? d0 : o0;
                const unsigned p3 = odd ? d1 : o1;
                const int sh = odd ? 16 : 0;
                float hp[4];
                hp[0] = bfbits2f((p0 >> sh) & 0xffffu);
                hp[1] = bfbits2f((p1 >> sh) & 0xffffu);
                hp[2] = bfbits2f((p2 >> sh) & 0xffffu);
                hp[3] = bfbits2f((p3 >> sh) & 0xffffu);
                unsigned bb[4];
#pragma unroll
                for (int i = 0; i < 4; ++i) {
                    const float r_ = sigmoidf_fast(acc[0][mt][i]);
                    const float z_ = sigmoidf_fast(acc[1][mt][i]);
                    const float n_ = tanhf_fast(acc[2][mt][i] + r_ * acc[3][mt][i]);
                    const float hv = fmaf(z_, hp[i] - n_, n_);
                    bb[i] = f2bfbits(hv);
                }
                const unsigned lo  = bb[0] | (bb[1] << 16);
                const unsigned hi  = bb[2] | (bb[3] << 16);
                const unsigned olo = (unsigned)__shfl_xor((int)lo, 1);
                const unsigned ohi = (unsigned)__shfl_xor((int)hi, 1);
                unsigned w0, w1;
                if (odd) {
                    w0 = (ohi & 0xffffu) | (hi << 16);
                    w1 = (ohi >> 16)     | (hi & 0xffff0000u);
                } else {
                    w0 = (lo & 0xffffu)  | (olo << 16);
                    w1 = (lo >> 16)      | (olo & 0xffff0000u);
                }
                *(unsigned*)((char*)hs + hsoff(rowA,     colb)) = w0;
                *(unsigned*)((char*)hs + hsoff(rowA + 1, colb)) = w1;
            }
            bc0 = bn0; bc1 = bn1; bc2 = bn2; bc3 = bn3;
        }
        // ---- unit end: reload hf from hs (own rows -> no barrier needed) ----
        if (u < UNITS - 1) {
#pragma unroll
            for (int mt = 0; mt < 2; ++mt)
#pragma unroll
                for (int kc = 0; kc < 8; ++kc)
                    hf[mt][kc] = *(const bf16x8*)((const char*)hs +
                        hsoff(wave * 32 + mt * 16 + l15, kc * 32 + quad * 8));
        }
    }

    // ---- coalesced f32 flush of the final h (cross-wave reads) ----
    __syncthreads();
    {
        const int c8 = (tid & 31) * 8;
        const int r0 = tid >> 5;            // 0..15
#pragma unroll
        for (int i = 0; i < 16; ++i) {
            const int r = r0 + i * 16;      // 0..255
            const bf16x8 v = *(const bf16x8*)((const char*)hs + hsoff(r, c8));
            float4 a, b;
            a.x = (float)v[0]; a.y = (float)v[1]; a.z = (float)v[2]; a.w = (float)v[3];
            b.x = (float)v[4]; b.y = (float)v[5]; b.z = (float)v[6]; b.w = (float)v[7];
            float* o = out + (size_t)(m0 + r) * DIM + c8;
            *(float4*)o       = a;
            *(float4*)(o + 4) = b;
        }
    }
}

// ---------------------------------------------------------------------------
extern "C" void kernel_launch(void* const* d_in, const int* in_sizes, int n_in,
                              void* d_out, int out_size, void* d_ws, size_t ws_size,
                              hipStream_t stream) {
    const float* x   = (const float*)d_in[0];
    const float* Wih = (const float*)d_in[1];   // [8,768,256] f32
    const float* Whh = (const float*)d_in[2];   // [8,768,256] f32
    const float* bih = (const float*)d_in[3];   // [8,768] f32
    const float* bhh = (const float*)d_in[4];   // [8,768] f32
    const float* h0  = (const float*)d_in[5];   // [256] f32
    float* out = (float*)d_out;                 // [B,256] f32

    // ws layout: Wpk[2*WN bf16, fragment-stream order] | bcomb[8*1024 f32]
    bf16* Wpk    = (bf16*)d_ws;
    float* bcomb = (float*)(Wpk + 2 * WN);

    {
        const size_t total = 2 * WN / 8 + (size_t)UNITS * 1024;   // 401,408
        const int cblocks = (int)((total + 255) / 256);
        hipLaunchKernelGGL(convert_kernel, dim3(cblocks), dim3(256), 0, stream,
                           Wih, Whh, bih, bhh, Wpk, bcomb);
    }
    hipLaunchKernelGGL(gru_fused_kernel, dim3(BATCH / BM), dim3(512), 0, stream,
                       x, h0, Wpk, bcomb, out);
}

// Round 6
// 670.472 us; speedup vs baseline: 1.0821x; 1.0821x over previous
//
#include <hip/hip_runtime.h>
#include <hip/hip_bf16.h>

typedef __bf16 bf16;
typedef __bf16 bf16x4 __attribute__((ext_vector_type(4)));
typedef __bf16 bf16x8 __attribute__((ext_vector_type(8)));
typedef float f32x4 __attribute__((ext_vector_type(4)));

#define GLD16(gp, sp) __builtin_amdgcn_global_load_lds( \
    (const __attribute__((address_space(1))) void*)(gp), \
    (__attribute__((address_space(3))) void*)(sp), 16, 0, 0)

#define FENCE() asm volatile("" ::: "memory")
#define BARRIER() do { FENCE(); __builtin_amdgcn_s_barrier(); FENCE(); } while (0)

constexpr int UNITS = 8;
constexpr int BATCH = 65536;
constexpr int DIM   = 256;          // I == H == 256
constexpr int BM    = 256;          // rows per block (1 block/CU, 8 waves)
constexpr int BN    = 16;           // j-tile columns
constexpr int BK    = 64;           // K per staged buffer (2 MFMA k-chunks)
constexpr int JT    = DIM / BN;     // 16 j-tiles
constexpr int PAIRS = DIM / BK;     // 4 staged buffers per jt
constexpr int STEPS_PER_UNIT = JT * PAIRS;          // 64
constexpr int TOT_STEPS = UNITS * STEPS_PER_UNIT;   // 512
constexpr int WTILE = 3 * BN * BK;  // 3072 bf16 = 6 KB (wi or wh)
constexpr size_t WN = (size_t)UNITS * 3 * DIM * DIM;  // per weight tensor

__device__ __forceinline__ float sigmoidf_fast(float x) {
    return 1.0f / (1.0f + __expf(-x));
}
__device__ __forceinline__ float tanhf_fast(float x) {
    float y = fminf(fmaxf(x, -15.0f), 15.0f);
    float e = __expf(-2.0f * y);
    return (1.0f - e) / (1.0f + e);
}
// swizzled h tile (512B rows): XOR row bits into the 16B-slot bits
__device__ __forceinline__ unsigned hsoff(int row, int col) {
    return (unsigned)((row * DIM + col) * 2) ^ (unsigned)((row & 7) << 4);
}
__device__ __forceinline__ float bfbits2f(unsigned b) {
    return __builtin_bit_cast(float, b << 16);
}
__device__ __forceinline__ unsigned f2bfbits(float f) {
    return (unsigned)__builtin_bit_cast(unsigned short, (bf16)f);
}

// ---------------------------------------------------------------------------
// f32 -> bf16 weights, plus combined gate biases:
// bcomb[u][0..256)=bih_r+bhh_r, [256..512)=bih_z+bhh_z, [512..768)=bih_n, [768..1024)=bhh_n
__global__ void convert_kernel(const float* __restrict__ Wih,
                               const float* __restrict__ Whh,
                               const float* __restrict__ bih,
                               const float* __restrict__ bhh,
                               bf16* __restrict__ Wihbf,
                               bf16* __restrict__ Whhbf,
                               float* __restrict__ bcomb)
{
    const size_t W4 = 2 * WN / 4;
    size_t i = (size_t)blockIdx.x * blockDim.x + threadIdx.x;
    if (i < W4) {
        size_t e = i * 4;
        const float* src = (e < WN) ? Wih : Whh;
        bf16* dst        = (e < WN) ? Wihbf : Whhbf;
        size_t off       = (e < WN) ? e : e - WN;
        const float4 v = *(const float4*)(src + off);
        bf16x4 o;
        o[0] = (bf16)v.x; o[1] = (bf16)v.y; o[2] = (bf16)v.z; o[3] = (bf16)v.w;
        *(bf16x4*)(dst + off) = o;
    } else {
        size_t j = i - W4;
        if (j < (size_t)UNITS * 1024) {
            int u = (int)(j >> 10), t = (int)(j & 1023);
            const float* bi = bih + u * 768;
            const float* bh = bhh + u * 768;
            float v;
            if (t < 512)      v = bi[t] + bh[t];
            else if (t < 768) v = bi[t];
            else              v = bh[t - 256];
            bcomb[u * 1024 + t] = v;
        }
    }
}

// ---------------------------------------------------------------------------
// Stage the (u,jt,pair) weight buffer: wi = 48 rows (3 gates x 16 j) x 64 k,
// wh same -> 12 x 1KB chunks (8 rows x 128B each).  R2/R4-verified geometry:
// 128B rows, conflict-free read key (l15&7); global source k pre-swizzled so
// the linear global_load_lds destination yields the swizzled layout.
__device__ __forceinline__ void stage_w(const bf16* __restrict__ Wihbf,
                                        const bf16* __restrict__ Whhbf,
                                        bf16* wb, int sg, int wave, int lane)
{
    const int u    = sg >> 6;
    const int jt   = (sg >> 2) & 15;
    const int pair = sg & 3;
    const int k0   = pair * 64;
    const bf16* Wi = Wihbf + (size_t)u * (3 * DIM * DIM);
    const bf16* Wh = Whhbf + (size_t)u * (3 * DIM * DIM);
    const int rr   = lane >> 3;                 // row-in-chunk 0..7
    const int scol = ((lane & 7) ^ rr) << 3;    // pre-swizzled k elems
    {   // chunk c = wave: c<6 -> wi chunk c, else wh chunk c-6
        const int c  = wave;
        const bf16* W = (c < 6) ? Wi : Wh;
        const int cc = (c < 6) ? c : c - 6;
        bf16* d = wb + ((c < 6) ? 0 : WTILE) + cc * 512;
        const int r = cc * 8 + rr;              // tile row 0..47
        const int grow = (r >> 4) * DIM + jt * BN + (r & 15);
        GLD16(W + (size_t)grow * DIM + k0 + scol, d);
    }
    if (wave < 4) {   // chunks 8..11 -> wh chunks 2..5
        const int cc = wave + 2;
        const int r = cc * 8 + rr;
        const int grow = (r >> 4) * DIM + jt * BN + (r & 15);
        GLD16(Wh + (size_t)grow * DIM + k0 + scol, wb + WTILE + cc * 512);
    }
}

// read one half-buffer (kc2 = 0/1) of B-fragments
#define READ6(BI, BH, WT, KC2) do {                                          \
    _Pragma("unroll")                                                        \
    for (int g_ = 0; g_ < 3; ++g_) {                                         \
        const int off_ = (g_ * BN + l15) * BK                                \
                       + ((((KC2) * 4 + quad) ^ (l15 & 7)) << 3);            \
        BI[g_] = *(const bf16x8*)((WT) + off_);                              \
        BH[g_] = *(const bf16x8*)((WT) + WTILE + off_);                      \
    }                                                                        \
} while (0)

// 12 MFMAs of one k-chunk (KCG compile-time).
// DEPENDENCY INTERLEAVE (the R6 change): all-x across 6 accumulators first,
// then all-h. Minimum distance between MFMAs sharing an accumulator goes
// 1 -> 6 issue slots (~116 cyc), covering matrix-pipe latency so the wave
// never stalls on an acc RAW hazard. Per-acc summation order is unchanged
// (x before h, same k order) -> bitwise-identical results.
#define MFMA12(BI, BH, KCG) do {                                             \
    acc[0][0] = __builtin_amdgcn_mfma_f32_16x16x32_bf16(xf[0][KCG], BI[0], acc[0][0], 0, 0, 0); \
    acc[1][0] = __builtin_amdgcn_mfma_f32_16x16x32_bf16(xf[0][KCG], BI[1], acc[1][0], 0, 0, 0); \
    acc[2][0] = __builtin_amdgcn_mfma_f32_16x16x32_bf16(xf[0][KCG], BI[2], acc[2][0], 0, 0, 0); \
    acc[0][1] = __builtin_amdgcn_mfma_f32_16x16x32_bf16(xf[1][KCG], BI[0], acc[0][1], 0, 0, 0); \
    acc[1][1] = __builtin_amdgcn_mfma_f32_16x16x32_bf16(xf[1][KCG], BI[1], acc[1][1], 0, 0, 0); \
    acc[2][1] = __builtin_amdgcn_mfma_f32_16x16x32_bf16(xf[1][KCG], BI[2], acc[2][1], 0, 0, 0); \
    acc[0][0] = __builtin_amdgcn_mfma_f32_16x16x32_bf16(hf[0][KCG], BH[0], acc[0][0], 0, 0, 0); \
    acc[1][0] = __builtin_amdgcn_mfma_f32_16x16x32_bf16(hf[0][KCG], BH[1], acc[1][0], 0, 0, 0); \
    acc[3][0] = __builtin_amdgcn_mfma_f32_16x16x32_bf16(hf[0][KCG], BH[2], acc[3][0], 0, 0, 0); \
    acc[0][1] = __builtin_amdgcn_mfma_f32_16x16x32_bf16(hf[1][KCG], BH[0], acc[0][1], 0, 0, 0); \
    acc[1][1] = __builtin_amdgcn_mfma_f32_16x16x32_bf16(hf[1][KCG], BH[1], acc[1][1], 0, 0, 0); \
    acc[3][1] = __builtin_amdgcn_mfma_f32_16x16x32_bf16(hf[1][KCG], BH[2], acc[3][1], 0, 0, 0); \
} while (0)

// ---------------------------------------------------------------------------
// Fused 8-unit GRU chain, 1 block/CU, 8 waves. Software-pipelined K-loop:
// each pair's kc2=1 MFMAs execute at the TOP of the next pair, BEFORE the
// vmcnt/barrier, so MFMA overlaps the CU-wide LDS read burst + barrier skew.
__global__ __launch_bounds__(512, 2)
void gru_fused_kernel(const float* __restrict__ xg,     // [B,256] f32
                      const float* __restrict__ h0g,    // [256] f32
                      const bf16* __restrict__ Wihbf,   // [8,768,256] bf16
                      const bf16* __restrict__ Whhbf,   // [8,768,256] bf16
                      const float* __restrict__ bcomb,  // [8,1024] f32
                      float* __restrict__ out)          // [B,256] f32
{
    __shared__ __align__(16) bf16 hs[BM * DIM];       // 128 KB
    __shared__ __align__(16) bf16 wbuf[2][2 * WTILE]; // 24 KB  => 152 KB

    const int tid  = threadIdx.x;
    const int wave = tid >> 6;      // 0..7
    const int lane = tid & 63;
    const int quad = lane >> 4;
    const int l15  = lane & 15;
    const int odd  = l15 & 1;
    const int m0   = blockIdx.x * BM;

    // ---- x m-tile -> persistent A-fragments (f32 load, bf16 convert) ----
    bf16x8 xf[2][8];
#pragma unroll
    for (int mt = 0; mt < 2; ++mt) {
        const int row = m0 + wave * 32 + mt * 16 + l15;
        const float* xr = xg + (size_t)row * DIM + quad * 8;
#pragma unroll
        for (int kc = 0; kc < 8; ++kc) {
            const float4 a = *(const float4*)(xr + kc * 32);
            const float4 b = *(const float4*)(xr + kc * 32 + 4);
            bf16x8 v;
            v[0]=(bf16)a.x; v[1]=(bf16)a.y; v[2]=(bf16)a.z; v[3]=(bf16)a.w;
            v[4]=(bf16)b.x; v[5]=(bf16)b.y; v[6]=(bf16)b.z; v[7]=(bf16)b.w;
            xf[mt][kc] = v;
        }
    }

    // ---- h0 -> hf A-fragments (broadcast) + hs init (own rows) ----
    bf16x8 hf[2][8];
#pragma unroll
    for (int kc = 0; kc < 8; ++kc) {
        const float4 a = *(const float4*)(h0g + kc * 32 + quad * 8);
        const float4 b = *(const float4*)(h0g + kc * 32 + quad * 8 + 4);
        bf16x8 v;
        v[0]=(bf16)a.x; v[1]=(bf16)a.y; v[2]=(bf16)a.z; v[3]=(bf16)a.w;
        v[4]=(bf16)b.x; v[5]=(bf16)b.y; v[6]=(bf16)b.z; v[7]=(bf16)b.w;
        hf[0][kc] = v;
        hf[1][kc] = v;
    }
#pragma unroll
    for (int mt = 0; mt < 2; ++mt)
#pragma unroll
        for (int kc = 0; kc < 8; ++kc)
            *(bf16x8*)((char*)hs + hsoff(wave * 32 + mt * 16 + l15,
                                         kc * 32 + quad * 8)) = hf[mt][kc];

    // ---- bias regs for (u=0, jt=0) + prologue stage ----
    float bc0, bc1, bc2, bc3;             // r, z, n_i, n_h biases (col jt*16+l15)
    float bn0 = 0.f, bn1 = 0.f, bn2 = 0.f, bn3 = 0.f;
    {
        const float* bp = bcomb + l15;
        bc0 = bp[0]; bc1 = bp[256]; bc2 = bp[512]; bc3 = bp[768];
    }
    stage_w(Wihbf, Whhbf, (bf16*)wbuf[0], 0, wave, lane);

    for (int u = 0; u < UNITS; ++u) {
        for (int jt = 0; jt < JT; ++jt) {
            // biases folded into accumulator init
            f32x4 acc[4][2];
#pragma unroll
            for (int mt = 0; mt < 2; ++mt) {
                acc[0][mt] = (f32x4){bc0, bc0, bc0, bc0};
                acc[1][mt] = (f32x4){bc1, bc1, bc1, bc1};
                acc[2][mt] = (f32x4){bc2, bc2, bc2, bc2};
                acc[3][mt] = (f32x4){bc3, bc3, bc3, bc3};
            }
            bf16x8 biA[3], bhA[3], biB[3], bhB[3];
            const int sgb = u * STEPS_PER_UNIT + jt * PAIRS;

#pragma unroll
            for (int pair = 0; pair < PAIRS; ++pair) {
                // finish the PREVIOUS pair's second k-chunk before the
                // barrier: overlaps this MFMA burst with other waves' reads
                // and with our own stage/barrier wait.
                if (pair == 1) MFMA12(biB, bhB, 1);
                if (pair == 2) MFMA12(biB, bhB, 3);
                if (pair == 3) MFMA12(biB, bhB, 5);

                asm volatile("s_waitcnt vmcnt(0)" ::: "memory");
                BARRIER();   // buf[pair&1] globally ready
                const bf16* wt = wbuf[pair & 1];
                READ6(biA, bhA, wt, 0);
                if (sgb + pair + 1 < TOT_STEPS)
                    stage_w(Wihbf, Whhbf, (bf16*)wbuf[(pair + 1) & 1],
                            sgb + pair + 1, wave, lane);
                if (pair == 1) {   // prefetch next jt's biases
                    const int njt = (jt + 1) & 15;
                    const int nu  = (jt == JT - 1) ? u + 1 : u;
                    if (nu < UNITS) {
                        const float* bp = bcomb + nu * 1024 + njt * BN + l15;
                        bn0 = bp[0]; bn1 = bp[256]; bn2 = bp[512]; bn3 = bp[768];
                    }
                }
                if (pair == 0) MFMA12(biA, bhA, 0);
                if (pair == 1) MFMA12(biA, bhA, 2);
                if (pair == 2) MFMA12(biA, bhA, 4);
                if (pair == 3) MFMA12(biA, bhA, 6);
                READ6(biB, bhB, wt, 1);
            }
            MFMA12(biB, bhB, 7);   // pipeline flush for this jt

            // ---- epilogue: activations, write h_new through to hs ----
            // biases already inside acc. C/D layout: col = l15, row = quad*4+i.
#pragma unroll
            for (int mt = 0; mt < 2; ++mt) {
                const int rbase = wave * 32 + mt * 16 + quad * 4;
                const int rowA  = rbase + 2 * odd;
                const int colb  = jt * BN + (l15 & ~1);
                const unsigned d0 = *(const unsigned*)((const char*)hs + hsoff(rowA,     colb));
                const unsigned d1 = *(const unsigned*)((const char*)hs + hsoff(rowA + 1, colb));
                const unsigned o0 = (unsigned)__shfl_xor((int)d0, 1);
                const unsigned o1 = (unsigned)__shfl_xor((int)d1, 1);
                const unsigned p0 = odd ? o0 : d0;
                const unsigned p1 = odd ? o1 : d1;
                const unsigned p2 = odd ? d0 : o0;
                const unsigned p3 = odd ? d1 : o1;
                const int sh = odd ? 16 : 0;
                float hp[4];
                hp[0] = bfbits2f((p0 >> sh) & 0xffffu);
                hp[1] = bfbits2f((p1 >> sh) & 0xffffu);
                hp[2] = bfbits2f((p2 >> sh) & 0xffffu);
                hp[3] = bfbits2f((p3 >> sh) & 0xffffu);
                unsigned bb[4];
#pragma unroll
                for (int i = 0; i < 4; ++i) {
                    const float r_ = sigmoidf_fast(acc[0][mt][i]);
                    const float z_ = sigmoidf_fast(acc[1][mt][i]);
                    const float n_ = tanhf_fast(acc[2][mt][i] + r_ * acc[3][mt][i]);
                    const float hv = fmaf(z_, hp[i] - n_, n_);
                    bb[i] = f2bfbits(hv);
                }
                const unsigned lo  = bb[0] | (bb[1] << 16);
                const unsigned hi  = bb[2] | (bb[3] << 16);
                const unsigned olo = (unsigned)__shfl_xor((int)lo, 1);
                const unsigned ohi = (unsigned)__shfl_xor((int)hi, 1);
                unsigned w0, w1;
                if (odd) {
                    w0 = (ohi & 0xffffu) | (hi << 16);
                    w1 = (ohi >> 16)     | (hi & 0xffff0000u);
                } else {
                    w0 = (lo & 0xffffu)  | (olo << 16);
                    w1 = (lo >> 16)      | (olo & 0xffff0000u);
                }
                *(unsigned*)((char*)hs + hsoff(rowA,     colb)) = w0;
                *(unsigned*)((char*)hs + hsoff(rowA + 1, colb)) = w1;
            }
            bc0 = bn0; bc1 = bn1; bc2 = bn2; bc3 = bn3;
        }
        // ---- unit end: reload hf from hs (own rows -> no barrier needed) ----
        if (u < UNITS - 1) {
#pragma unroll
            for (int mt = 0; mt < 2; ++mt)
#pragma unroll
                for (int kc = 0; kc < 8; ++kc)
                    hf[mt][kc] = *(const bf16x8*)((const char*)hs +
                        hsoff(wave * 32 + mt * 16 + l15, kc * 32 + quad * 8));
        }
    }

    // ---- coalesced f32 flush of the final h (cross-wave reads) ----
    __syncthreads();
    {
        const int c8 = (tid & 31) * 8;
        const int r0 = tid >> 5;            // 0..15
#pragma unroll
        for (int i = 0; i < 16; ++i) {
            const int r = r0 + i * 16;      // 0..255
            const bf16x8 v = *(const bf16x8*)((const char*)hs + hsoff(r, c8));
            float4 a, b;
            a.x = (float)v[0]; a.y = (float)v[1]; a.z = (float)v[2]; a.w = (float)v[3];
            b.x = (float)v[4]; b.y = (float)v[5]; b.z = (float)v[6]; b.w = (float)v[7];
            float* o = out + (size_t)(m0 + r) * DIM + c8;
            *(float4*)o       = a;
            *(float4*)(o + 4) = b;
        }
    }
}

// ---------------------------------------------------------------------------
extern "C" void kernel_launch(void* const* d_in, const int* in_sizes, int n_in,
                              void* d_out, int out_size, void* d_ws, size_t ws_size,
                              hipStream_t stream) {
    const float* x   = (const float*)d_in[0];
    const float* Wih = (const float*)d_in[1];   // [8,768,256] f32
    const float* Whh = (const float*)d_in[2];   // [8,768,256] f32
    const float* bih = (const float*)d_in[3];   // [8,768] f32
    const float* bhh = (const float*)d_in[4];   // [8,768] f32
    const float* h0  = (const float*)d_in[5];   // [256] f32
    float* out = (float*)d_out;                 // [B,256] f32

    // ws layout: Wihbf[WN] | Whhbf[WN] (bf16) | bcomb[8*1024] (f32)
    bf16* Wihbf  = (bf16*)d_ws;
    bf16* Whhbf  = Wihbf + WN;
    float* bcomb = (float*)(Whhbf + WN);

    {
        const size_t total = 2 * WN / 4 + (size_t)UNITS * 1024;
        const int cblocks = (int)((total + 255) / 256);
        hipLaunchKernelGGL(convert_kernel, dim3(cblocks), dim3(256), 0, stream,
                           Wih, Whh, bih, bhh, Wihbf, Whhbf, bcomb);
    }
    hipLaunchKernelGGL(gru_fused_kernel, dim3(BATCH / BM), dim3(512), 0, stream,
                       x, h0, Wihbf, Whhbf, bcomb, out);
}